// Round 10
// baseline (211.794 us; speedup 1.0000x reference)
//
#include <hip/hip_runtime.h>
#include <hip/hip_bf16.h>
#include <stdint.h>

typedef unsigned short u16;
typedef __bf16 bf16x8 __attribute__((ext_vector_type(8)));
typedef float f32x4 __attribute__((ext_vector_type(4)));
typedef float f32x16 __attribute__((ext_vector_type(16)));
typedef unsigned int u32x4 __attribute__((ext_vector_type(4)));
typedef unsigned int u32x2 __attribute__((ext_vector_type(2)));

#define S_LEN 2048
#define DMODEL 1024
#define NHEAD 16
#define DHEAD 64
#define MROWS 4096  // B*S
#define EXP2SCALE 0.180336880112f  // 0.125 * log2(e)

__device__ __forceinline__ u16 f2b(float f) {
  __hip_bfloat16 h = __float2bfloat16(f);
  union { __hip_bfloat16 h; u16 u; } c;
  c.h = h;
  return c.u;
}
__device__ __forceinline__ unsigned int pk2(float lo, float hi) {
  return (unsigned int)f2b(lo) | ((unsigned int)f2b(hi) << 16);
}
// packed f32->bf16 pair (HW cvt_pk, RNE): dst = {lo: cvt(a), hi: cvt(b)}
__device__ __forceinline__ unsigned int cvtpk(float a, float b) {
  unsigned int r;
  asm("v_cvt_pk_bf16_f32 %0, %1, %2" : "=v"(r) : "v"(a), "v"(b));
  return r;
}
// swap a's high 32 lanes with b's low 32 lanes
__device__ __forceinline__ void plswap(unsigned int &a, unsigned int &b) {
  auto r = __builtin_amdgcn_permlane32_swap((int)a, (int)b, false, false);
  a = (unsigned int)r[0];
  b = (unsigned int)r[1];
}

// async global->LDS, 16B per lane: LDS dest = wave-uniform base + lane*16.
__device__ __forceinline__ void gload16(const void* g, void* l) {
  __builtin_amdgcn_global_load_lds(
      (const __attribute__((address_space(1))) unsigned int*)(uintptr_t)g,
      (__attribute__((address_space(3))) unsigned int*)(uintptr_t)l,
      16, 0, 0);
}

// ------------- prep: fused activation cvt (z 0..2) + weight transpose (z 3..6)
__global__ __launch_bounds__(256) void prep(
    const float* __restrict__ q, const float* __restrict__ k, const float* __restrict__ v,
    const float* __restrict__ Wq, const float* __restrict__ Wk,
    const float* __restrict__ Wv, const float* __restrict__ Wo,
    u16* __restrict__ Qx, u16* __restrict__ Kx, u16* __restrict__ Vx,
    u16* __restrict__ Wqt, u16* __restrict__ Wkt,
    u16* __restrict__ Wvt, u16* __restrict__ Wot) {
  __shared__ u16 tile[64][65];
  const int z = blockIdx.z;
  const int tid = threadIdx.x;
  if (z < 3) {
    const float* src = (z == 0) ? q : (z == 1) ? k : v;
    u16* dst = (z == 0) ? Qx : (z == 1) ? Kx : Vx;
    const size_t i8 = ((size_t)blockIdx.x * 256 + tid) * 8;
    float4 a = *(const float4*)(src + i8);
    float4 b = *(const float4*)(src + i8 + 4);
    u16 o[8];
    o[0] = f2b(a.x); o[1] = f2b(a.y); o[2] = f2b(a.z); o[3] = f2b(a.w);
    o[4] = f2b(b.x); o[5] = f2b(b.y); o[6] = f2b(b.z); o[7] = f2b(b.w);
    *(u32x4*)(dst + i8) = *(const u32x4*)o;
    return;
  }
  if (blockIdx.x >= 256) return;
  const int zz = z - 3;
  const float* W = (zz == 0) ? Wq : (zz == 1) ? Wk : (zz == 2) ? Wv : Wo;
  u16* Wt = (zz == 0) ? Wqt : (zz == 1) ? Wkt : (zz == 2) ? Wvt : Wot;
  const int n0 = (blockIdx.x & 15) * 64, k0 = (blockIdx.x >> 4) * 64;
#pragma unroll
  for (int j = 0; j < 16; j++) {
    int idx = j * 256 + tid;
    int r = idx >> 6, c = idx & 63;
    tile[r][c] = f2b(W[(size_t)(k0 + r) * DMODEL + n0 + c]);
  }
  __syncthreads();
#pragma unroll
  for (int j = 0; j < 16; j++) {
    int idx = j * 256 + tid;
    int r = idx >> 6, c = idx & 63;
    Wt[(size_t)(n0 + r) * DMODEL + k0 + c] = tile[c][r];
  }
}

// ---------------- GEMM: C[M,1024] = A(bf16) * Bt(bf16)^T + bias(f32)
// v10: BM x 128 tile, BK=32, TRIPLE-buffered LDS with ONE raw s_barrier per
// K-step and COUNTED vmcnt (T3/T4): loads for step k+2 issued right after
// barrier k -> 2 full compute phases of latency slack; never drain vmcnt to 0
// in the main loop. Race-free without timing assumptions: explicit lgkmcnt(0)
// before the barrier guarantees all waves' step-(k-1) ds_reads are consumed
// before any wave overwrites that buffer.
// Bank swizzle for 64B row stride: XOR key (row>>1)&3 -> 2 lanes/bank-group
// per quarter-wave (free); source pre-swizzled for gload_lds (rule #21).
// XCD-chunked block swizzle (T1). Shared LDS passed in (R6 bug fix).
// MODE: 0 = bf16 row-major C; 1 = f32 row-major C; 2 = bf16 transposed V-out
//       (Vt[(b*1024 + col)][s]); 3 = bf16 row-major C pre-scaled by EXP2SCALE
template <int MODE, int BM>
__device__ __forceinline__ void gemm_body(const u16* __restrict__ A,
                                          const u16* __restrict__ Bt,
                                          const float* __restrict__ bias,
                                          void* __restrict__ Cv,
                                          u16* __restrict__ As,
                                          u16* __restrict__ Bs) {
  constexpr int K = DMODEL;
  constexpr int NS = K / 32;       // 32 K-steps of BK=32
  constexpr int MB = MROWS / BM;   // brow count per slice
  constexpr int TA = BM / 64;      // A gload16 per thread per step
  constexpr int NI = BM / 32;      // i-fragments per wave
  constexpr int ASZ = BM * 32;     // u16 per A buffer
  constexpr int BSZ = 128 * 32;    // u16 per B buffer
  constexpr int VW = TA + 2;       // gloads in flight per wave per step
  const int tid = threadIdx.x;
  const int wave = tid >> 6, lane = tid & 63;
  const int quad = lane >> 4, l15 = lane & 15;
  const int wr = wave >> 1, wc = wave & 1;
  const int lid = blockIdx.y * 8 + blockIdx.x;   // 8*MB blocks/slice, 8 XCDs
  const int sw = (lid & 7) * MB + (lid >> 3);    // bijective chunked swizzle
  const int bcol = sw & 7, brow = sw >> 3;

  f32x4 acc[NI][4] = {};

  // stage step s into buffer b: linear LDS dest, inverse-swizzled source
  auto issue = [&](int b, int s) {
#pragma unroll
    for (int t = 0; t < TA; t++) {
      const int slot = t * 256 + wave * 64 + lane;       // BM*4 slots of 16B
      const int row = slot >> 2;
      const int cgc = ((slot & 3) ^ ((row >> 1) & 3)) << 3;
      gload16(A + (size_t)(brow * BM + row) * K + s * 32 + cgc,
              As + b * ASZ + (t * 256 + wave * 64) * 8);
    }
#pragma unroll
    for (int t = 0; t < 2; t++) {
      const int slot = t * 256 + wave * 64 + lane;       // 512 slots of 16B
      const int row = slot >> 2;
      const int cgc = ((slot & 3) ^ ((row >> 1) & 3)) << 3;
      gload16(Bt + (size_t)(bcol * 128 + row) * K + s * 32 + cgc,
              Bs + b * BSZ + (t * 256 + wave * 64) * 8);
    }
  };

  issue(0, 0);
  issue(1, 1);

#pragma unroll 1
  for (int k = 0; k < NS; ++k) {
    // my step-(k-1) ds_reads consumed (so buffer reuse below is safe) ...
    asm volatile("s_waitcnt lgkmcnt(0)" ::: "memory");
    // ... and my step-k gloads have landed; step-k+1's stay in flight
    if (k == NS - 1)
      asm volatile("s_waitcnt vmcnt(0)" ::: "memory");
    else
      asm volatile("s_waitcnt vmcnt(%0)" :: "i"(VW) : "memory");
    __builtin_amdgcn_s_barrier();
    __builtin_amdgcn_sched_barrier(0);
    if (k + 2 < NS) issue((k + 2) % 3, k + 2);   // 2-step-ahead prefetch

    const u16* Ab = As + (k % 3) * ASZ;
    const u16* Bb = Bs + (k % 3) * BSZ;
    bf16x8 af[NI], bfm[4];
#pragma unroll
    for (int i = 0; i < NI; i++)
      af[i] = *(const bf16x8*)(Ab + (wr * (BM / 2) + i * 16 + l15) * 32 +
                               ((quad ^ ((l15 >> 1) & 3)) << 3));
#pragma unroll
    for (int j = 0; j < 4; j++)
      bfm[j] = *(const bf16x8*)(Bb + (wc * 64 + j * 16 + l15) * 32 +
                                ((quad ^ ((l15 >> 1) & 3)) << 3));
    __builtin_amdgcn_s_setprio(1);
#pragma unroll
    for (int i = 0; i < NI; i++)
#pragma unroll
      for (int j = 0; j < 4; j++)
        acc[i][j] = __builtin_amdgcn_mfma_f32_16x16x32_bf16(af[i], bfm[j], acc[i][j], 0, 0, 0);
    __builtin_amdgcn_s_setprio(0);
  }

#pragma unroll
  for (int i = 0; i < NI; i++)
#pragma unroll
    for (int j = 0; j < 4; j++) {
      const int col = bcol * 128 + wc * 64 + j * 16 + l15;
      const float bv = bias[col];
      if (MODE == 2) {
        const int srow = brow * BM + wr * (BM / 2) + i * 16 + quad * 4;
        const int bb = srow >> 11, s = srow & (S_LEN - 1);
        u32x2 pd;
        pd.x = pk2(acc[i][j][0] + bv, acc[i][j][1] + bv);
        pd.y = pk2(acc[i][j][2] + bv, acc[i][j][3] + bv);
        *(u32x2*)((u16*)Cv + ((size_t)(bb * 1024 + col)) * S_LEN + s) = pd;
      } else {
#pragma unroll
        for (int r = 0; r < 4; r++) {
          const int row = brow * BM + wr * (BM / 2) + i * 16 + quad * 4 + r;
          if (MODE == 1)
            ((float*)Cv)[(size_t)row * DMODEL + col] = acc[i][j][r] + bv;
          else if (MODE == 3)
            ((u16*)Cv)[(size_t)row * DMODEL + col] = f2b((acc[i][j][r] + bv) * EXP2SCALE);
          else
            ((u16*)Cv)[(size_t)row * DMODEL + col] = f2b(acc[i][j][r] + bv);
        }
      }
    }
}

__global__ __launch_bounds__(256, 3) void gemm_qkv(
    const u16* __restrict__ Qx, const u16* __restrict__ Kx, const u16* __restrict__ Vx,
    const u16* __restrict__ Wqt, const u16* __restrict__ Wkt, const u16* __restrict__ Wvt,
    const float* __restrict__ bq, const float* __restrict__ bk, const float* __restrict__ bv,
    u16* __restrict__ Qp, u16* __restrict__ Kp, u16* __restrict__ Vt) {
  __shared__ u16 As[3 * 128 * 32];   // 24 KB
  __shared__ u16 Bs[3 * 128 * 32];   // 24 KB
  const int z = blockIdx.z;
  if (z == 2) {
    gemm_body<2, 128>(Vx, Wvt, bv, Vt, As, Bs);
  } else if (z == 0) {
    gemm_body<3, 128>(Qx, Wqt, bq, Qp, As, Bs);   // Q pre-scaled by exp2-scale
  } else {
    gemm_body<0, 128>(Kx, Wkt, bk, Kp, As, Bs);
  }
}

// BM=64: 512 blocks -> 2 blocks/CU for the single-slice output GEMM
__global__ __launch_bounds__(256, 4) void gemm_out(
    const u16* __restrict__ A, const u16* __restrict__ Bt,
    const float* __restrict__ bias, float* __restrict__ C) {
  __shared__ u16 As[3 * 64 * 32];    // 12 KB
  __shared__ u16 Bs[3 * 128 * 32];   // 24 KB
  gemm_body<1, 64>(A, Bt, bias, C, As, Bs);
}

// ---------------- flash attention, v8 (proven 49us): 8-wave split-K, K+V LDS
#define TILE_COMPUTE(ksb, vsb)                                                     \
  do {                                                                             \
    f32x16 sA = {}, sB = {};                                                       \
    __builtin_amdgcn_s_setprio(1);                                                 \
    _Pragma("unroll") for (int c = 0; c < 4; c++) {                                \
      bf16x8 ka0 = *(const bf16x8*)((ksb) + off[c]);                               \
      bf16x8 ka1 = *(const bf16x8*)((ksb) + off[c] + 2048);                        \
      sA = __builtin_amdgcn_mfma_f32_32x32x16_bf16(ka0, qf[c], sA, 0, 0, 0);       \
      sB = __builtin_amdgcn_mfma_f32_32x32x16_bf16(ka1, qf[c], sB, 0, 0, 0);       \
    }                                                                              \
    __builtin_amdgcn_s_setprio(0);                                                 \
    bf16x8 pf[4];                                                                  \
    _Pragma("unroll") for (int kb = 0; kb < 2; kb++) {                             \
      const f32x16 s = kb ? sB : sA;                                               \
      unsigned int cc[8];                                                          \
      _Pragma("unroll") for (int m = 0; m < 8; m++)                                \
        cc[m] = cvtpk(__builtin_amdgcn_exp2f(s[2 * m]),                            \
                      __builtin_amdgcn_exp2f(s[2 * m + 1]));                       \
      plswap(cc[0], cc[2]);                                                        \
      plswap(cc[1], cc[3]);                                                        \
      plswap(cc[4], cc[6]);                                                        \
      plswap(cc[5], cc[7]);                                                        \
      union { unsigned int u[4]; bf16x8 v; } f0, f1;                               \
      f0.u[0] = cc[0]; f0.u[1] = cc[1]; f0.u[2] = cc[2]; f0.u[3] = cc[3];          \
      f1.u[0] = cc[4]; f1.u[1] = cc[5]; f1.u[2] = cc[6]; f1.u[3] = cc[7];          \
      pf[2 * kb] = f0.v; pf[2 * kb + 1] = f1.v;                                    \
    }                                                                              \
    __builtin_amdgcn_s_setprio(1);                                                 \
    _Pragma("unroll") for (int g = 0; g < 4; g++) {                                \
      bf16x8 v0 = *(const bf16x8*)((vsb) + off[g]);                                \
      bf16x8 v1 = *(const bf16x8*)((vsb) + off[g] + 2048);                         \
      lacc  = __builtin_amdgcn_mfma_f32_32x32x16_bf16(pf[g], ones, lacc, 0, 0, 0); \
      oacc0 = __builtin_amdgcn_mfma_f32_32x32x16_bf16(pf[g], v0, oacc0, 0, 0, 0);  \
      oacc1 = __builtin_amdgcn_mfma_f32_32x32x16_bf16(pf[g], v1, oacc1, 0, 0, 0);  \
    }                                                                              \
    __builtin_amdgcn_s_setprio(0);                                                 \
  } while (0)

// each wave stages 4 KB (4 gloads) of its assigned tile region per step
#define ISSUE(buf, kt)                                                            \
  do {                                                                            \
    if (wave < 4) {                                                               \
      const u16* g = srcK + (size_t)(kt) * 64 * DMODEL;                           \
      _Pragma("unroll") for (int j = 0; j < 4; j++)                               \
        gload16(g + (size_t)j * 8 * DMODEL, dst0 + (buf) * 4096 + j * 512);       \
    } else {                                                                      \
      const u16* g = srcV + (kt) * 64;                                            \
      _Pragma("unroll") for (int j = 0; j < 4; j++)                               \
        gload16(g + (size_t)j * 8 * S_LEN, dst0 + (buf) * 4096 + j * 512);        \
    }                                                                             \
  } while (0)

__global__ __launch_bounds__(512, 4) void attn(const u16* __restrict__ Qp,
                                               const u16* __restrict__ Kp,
                                               const u16* __restrict__ Vt,
                                               u16* __restrict__ Op) {
  // 64 KB: Ks[kh][buf][64*64] at 0, Vs[kh][buf][64*64] at 16384 (u16 units)
  __shared__ u16 LB[32768];

  const int tid = threadIdx.x;
  const int wave = tid >> 6, lane = tid & 63;
  const int row31 = lane & 31, hl = lane >> 5;
  const int qg = wave & 3, kh = wave >> 2;     // compute roles

  // XCD-chunked swizzle over 512 blocks
  const int id = blockIdx.x + (blockIdx.y << 4) + (blockIdx.z << 8);
  const int sw = ((id & 7) << 6) + (id >> 3);
  const int qt = sw & 15, h = (sw >> 4) & 15, b = sw >> 8;
  const int s0 = qt * 128;

  const size_t baseK = ((size_t)(b * S_LEN)) * DMODEL + h * DHEAD;
  const size_t baseV = ((size_t)((b * NHEAD + h) * DHEAD)) * S_LEN;

  // staging roles: waves 0-3 stage K, 4-7 stage V; khd = key-half staged,
  // sub = which 32-row half of the 64-row tile. Pre-swizzled source (rule #21).
  const int sub = wave & 1, khd = (wave >> 1) & 1;
  const int rl = lane >> 3, cl = lane & 7;
  const int cg8 = (cl ^ rl) << 3;
  const u16* srcK = Kp + baseK + (size_t)(khd * 1024 + sub * 32 + rl) * DMODEL + cg8;
  const u16* srcV = Vt + baseV + (size_t)(sub * 32 + rl) * S_LEN + khd * 1024 + cg8;
  u16* dst0 = LB + (wave >= 4 ? 16384 : 0) + khd * 8192 + (sub * 32) * 64;

  // compute-side LDS bases for this wave's key-half
  const u16* kcb = LB + kh * 8192;
  const u16* vcb = LB + 16384 + kh * 8192;

  // LDS read offsets (u16), swizzled chunks
  int off[4];
#pragma unroll
  for (int c = 0; c < 4; c++)
    off[c] = row31 * 64 + ((((c << 1) + hl) ^ (row31 & 7)) << 3);

  // all-ones B fragment for the l-vector MFMA
  bf16x8 ones;
  {
    union { u16 a[8]; bf16x8 v; } c;
#pragma unroll
    for (int j = 0; j < 8; j++) c.a[j] = 0x3F80;
    ones = c.v;
  }

  // Q fragments (B-operand of S^T): col = q = row31, k = c*16 + hl*8 + j
  bf16x8 qf[4];
#pragma unroll
  for (int c = 0; c < 4; c++)
    qf[c] = *(const bf16x8*)(Qp +
        ((size_t)(b * S_LEN + s0 + qg * 32 + row31)) * DMODEL +
        h * DHEAD + c * 16 + hl * 8);

  f32x16 oacc0 = {}, oacc1 = {};
  f32x16 lacc = {};

  // prologue: tile 0 into buf0
  ISSUE(0, 0);

#pragma unroll 1
  for (int kt = 0; kt < 16; kt += 2) {
    __syncthreads();             // drains buf0 loads; prev buf1 reads done
    ISSUE(1, kt + 1);            // next tile flies under this compute
    TILE_COMPUTE(kcb, vcb);
    __syncthreads();             // drains buf1 loads; buf0 reads done
    if (kt + 2 < 16) ISSUE(0, kt + 2);
    TILE_COMPUTE(kcb + 4096, vcb + 4096);
  }

  // ---- split-K merge: kh=1 waves publish partials via LDS (48 KB of LB)
  __syncthreads();
  float* M = ((float*)LB) + qg * 3072;  // 12 KB region per q-group
  if (kh == 1) {
#pragma unroll
    for (int r = 0; r < 16; r++) {
      M[r * 64 + lane]        = oacc0[r];
      M[1024 + r * 64 + lane] = oacc1[r];
      M[2048 + r * 64 + lane] = lacc[r];
    }
  }
  __syncthreads();
  if (kh == 0) {
#pragma unroll
    for (int r = 0; r < 16; r++) {
      const float o0 = oacc0[r] + M[r * 64 + lane];
      const float o1 = oacc1[r] + M[1024 + r * 64 + lane];
      const float ls = lacc[r] + M[2048 + r * 64 + lane];
      const float inv = 1.0f / ls;
      const int qrow = (r & 3) + 8 * (r >> 2) + 4 * hl;
      const size_t rb = ((size_t)(b * S_LEN + s0 + qg * 32 + qrow)) * DMODEL + h * DHEAD;
      Op[rb + row31]      = f2b(o0 * inv);
      Op[rb + 32 + row31] = f2b(o1 * inv);
    }
  }
}

extern "C" void kernel_launch(void* const* d_in, const int* in_sizes, int n_in,
                              void* d_out, int out_size, void* d_ws, size_t ws_size,
                              hipStream_t stream) {
  const float* q  = (const float*)d_in[0];
  const float* k  = (const float*)d_in[1];
  const float* v  = (const float*)d_in[2];
  const float* Wq = (const float*)d_in[3];
  const float* bq = (const float*)d_in[4];
  const float* Wk = (const float*)d_in[5];
  const float* bk = (const float*)d_in[6];
  const float* Wv = (const float*)d_in[7];
  const float* bv = (const float*)d_in[8];
  const float* Wo = (const float*)d_in[9];
  const float* bo = (const float*)d_in[10];

  char* w = (char*)d_ws;
  const size_t WSZ = (size_t)DMODEL * DMODEL * 2;  // 2 MB per transposed weight
  const size_t XSZ = (size_t)MROWS * DMODEL * 2;   // 8 MB per bf16 activation
  u16* Wqt = (u16*)(w);
  u16* Wkt = (u16*)(w + WSZ);
  u16* Wvt = (u16*)(w + 2 * WSZ);
  u16* Wot = (u16*)(w + 3 * WSZ);
  u16* Qx  = (u16*)(w + 4 * WSZ);
  u16* Kx  = (u16*)(w + 4 * WSZ + XSZ);
  u16* Vx  = (u16*)(w + 4 * WSZ + 2 * XSZ);
  u16* Qp  = (u16*)(w + 4 * WSZ + 3 * XSZ);
  u16* Kp  = (u16*)(w + 4 * WSZ + 4 * XSZ);
  u16* Vt  = (u16*)(w + 4 * WSZ + 5 * XSZ);
  u16* Op  = (u16*)(w + 4 * WSZ + 6 * XSZ);  // total 64 MB

  prep<<<dim3(2048, 1, 7), 256, 0, stream>>>(q, k, v, Wq, Wk, Wv, Wo,
                                             Qx, Kx, Vx, Wqt, Wkt, Wvt, Wot);
  gemm_qkv<<<dim3(8, 32, 3), 256, 0, stream>>>(Qx, Kx, Vx, Wqt, Wkt, Wvt,
                                               bq, bk, bv, Qp, Kp, Vt);
  attn<<<dim3(16, 16, 2), 512, 0, stream>>>(Qp, Kp, Vt, Op);
  gemm_out<<<dim3(8, 64, 1), 256, 0, stream>>>(Op, Wot, bo, (float*)d_out);
}

// Round 11
// 209.336 us; speedup vs baseline: 1.0117x; 1.0117x over previous
//
#include <hip/hip_runtime.h>
#include <hip/hip_bf16.h>
#include <stdint.h>

typedef unsigned short u16;
typedef __bf16 bf16x8 __attribute__((ext_vector_type(8)));
typedef float f32x4 __attribute__((ext_vector_type(4)));
typedef float f32x16 __attribute__((ext_vector_type(16)));
typedef unsigned int u32x4 __attribute__((ext_vector_type(4)));
typedef unsigned int u32x2 __attribute__((ext_vector_type(2)));

#define S_LEN 2048
#define DMODEL 1024
#define NHEAD 16
#define DHEAD 64
#define MROWS 4096  // B*S
#define EXP2SCALE 0.180336880112f  // 0.125 * log2(e)

__device__ __forceinline__ u16 f2b(float f) {
  __hip_bfloat16 h = __float2bfloat16(f);
  union { __hip_bfloat16 h; u16 u; } c;
  c.h = h;
  return c.u;
}
__device__ __forceinline__ unsigned int pk2(float lo, float hi) {
  return (unsigned int)f2b(lo) | ((unsigned int)f2b(hi) << 16);
}
// packed f32->bf16 pair (HW cvt_pk, RNE): dst = {lo: cvt(a), hi: cvt(b)}
__device__ __forceinline__ unsigned int cvtpk(float a, float b) {
  unsigned int r;
  asm("v_cvt_pk_bf16_f32 %0, %1, %2" : "=v"(r) : "v"(a), "v"(b));
  return r;
}
// swap a's high 32 lanes with b's low 32 lanes
__device__ __forceinline__ void plswap(unsigned int &a, unsigned int &b) {
  auto r = __builtin_amdgcn_permlane32_swap((int)a, (int)b, false, false);
  a = (unsigned int)r[0];
  b = (unsigned int)r[1];
}

// async global->LDS, 16B per lane: LDS dest = wave-uniform base + lane*16.
__device__ __forceinline__ void gload16(const void* g, void* l) {
  __builtin_amdgcn_global_load_lds(
      (const __attribute__((address_space(1))) unsigned int*)(uintptr_t)g,
      (__attribute__((address_space(3))) unsigned int*)(uintptr_t)l,
      16, 0, 0);
}

// ------------- prep: fused activation cvt (z 0..2) + weight transpose (z 3..6)
__global__ __launch_bounds__(256) void prep(
    const float* __restrict__ q, const float* __restrict__ k, const float* __restrict__ v,
    const float* __restrict__ Wq, const float* __restrict__ Wk,
    const float* __restrict__ Wv, const float* __restrict__ Wo,
    u16* __restrict__ Qx, u16* __restrict__ Kx, u16* __restrict__ Vx,
    u16* __restrict__ Wqt, u16* __restrict__ Wkt,
    u16* __restrict__ Wvt, u16* __restrict__ Wot) {
  __shared__ u16 tile[64][65];
  const int z = blockIdx.z;
  const int tid = threadIdx.x;
  if (z < 3) {
    const float* src = (z == 0) ? q : (z == 1) ? k : v;
    u16* dst = (z == 0) ? Qx : (z == 1) ? Kx : Vx;
    const size_t i8 = ((size_t)blockIdx.x * 256 + tid) * 8;
    float4 a = *(const float4*)(src + i8);
    float4 b = *(const float4*)(src + i8 + 4);
    u16 o[8];
    o[0] = f2b(a.x); o[1] = f2b(a.y); o[2] = f2b(a.z); o[3] = f2b(a.w);
    o[4] = f2b(b.x); o[5] = f2b(b.y); o[6] = f2b(b.z); o[7] = f2b(b.w);
    *(u32x4*)(dst + i8) = *(const u32x4*)o;
    return;
  }
  if (blockIdx.x >= 256) return;
  const int zz = z - 3;
  const float* W = (zz == 0) ? Wq : (zz == 1) ? Wk : (zz == 2) ? Wv : Wo;
  u16* Wt = (zz == 0) ? Wqt : (zz == 1) ? Wkt : (zz == 2) ? Wvt : Wot;
  const int n0 = (blockIdx.x & 15) * 64, k0 = (blockIdx.x >> 4) * 64;
#pragma unroll
  for (int j = 0; j < 16; j++) {
    int idx = j * 256 + tid;
    int r = idx >> 6, c = idx & 63;
    tile[r][c] = f2b(W[(size_t)(k0 + r) * DMODEL + n0 + c]);
  }
  __syncthreads();
#pragma unroll
  for (int j = 0; j < 16; j++) {
    int idx = j * 256 + tid;
    int r = idx >> 6, c = idx & 63;
    Wt[(size_t)(n0 + r) * DMODEL + k0 + c] = tile[c][r];
  }
}

// ---------------- GEMM: C[M,1024] = A(bf16) * Bt(bf16)^T + bias(f32)
// v11: BM x 128 tile, BK=32, DOUBLE-buffered LDS with ONE __syncthreads per
// K-step (proven attn pattern): barrier k drains step-k loads AND closes
// step-(k-1) reads; then step-(k+1) loads are issued into the other buffer
// and fly UNDER step-k's MFMA compute (v9/v10 staged serially: no overlap).
// Same 32KB LDS / occupancy as v9. Bank swizzle for 64B rows: (row>>1)&3 XOR
// (verified v10); source pre-swizzled for gload_lds (rule #21). XCD swizzle.
// MODE 2 epilogue: C-tile staged in LDS (reuses A/B bufs) with XOR layout,
// then 16B-coalesced Vt writes (old path: scattered 8B stores, 4KB stride).
// MODE: 0 = bf16 row-major C; 1 = f32 row-major C; 2 = bf16 transposed V-out
//       (Vt[(b*1024 + col)][s]); 3 = bf16 row-major C pre-scaled by EXP2SCALE
template <int MODE, int BM>
__device__ __forceinline__ void gemm_body(const u16* __restrict__ A,
                                          const u16* __restrict__ Bt,
                                          const float* __restrict__ bias,
                                          void* __restrict__ Cv,
                                          u16* __restrict__ LB) {
  constexpr int K = DMODEL;
  constexpr int NS = K / 32;       // 32 K-steps of BK=32
  constexpr int MB = MROWS / BM;   // brow count per slice
  constexpr int TA = BM / 64;      // A gload16 per thread per step
  constexpr int NI = BM / 32;      // i-fragments per wave
  constexpr int ASZ = BM * 32;     // u16 per A buffer
  constexpr int BSZ = 128 * 32;    // u16 per B buffer
  u16* As = LB;                    // 2 x ASZ
  u16* Bs = LB + 2 * ASZ;          // 2 x BSZ
  const int tid = threadIdx.x;
  const int wave = tid >> 6, lane = tid & 63;
  const int quad = lane >> 4, l15 = lane & 15;
  const int wr = wave >> 1, wc = wave & 1;
  const int lid = blockIdx.y * 8 + blockIdx.x;   // 8*MB blocks/slice, 8 XCDs
  const int sw = (lid & 7) * MB + (lid >> 3);    // bijective chunked swizzle
  const int bcol = sw & 7, brow = sw >> 3;

  f32x4 acc[NI][4] = {};

  // stage step s into buffer b: linear LDS dest, inverse-swizzled source
  auto issue = [&](int b, int s) {
#pragma unroll
    for (int t = 0; t < TA; t++) {
      const int slot = t * 256 + wave * 64 + lane;       // BM*4 slots of 16B
      const int row = slot >> 2;
      const int cgc = ((slot & 3) ^ ((row >> 1) & 3)) << 3;
      gload16(A + (size_t)(brow * BM + row) * K + s * 32 + cgc,
              As + b * ASZ + (t * 256 + wave * 64) * 8);
    }
#pragma unroll
    for (int t = 0; t < 2; t++) {
      const int slot = t * 256 + wave * 64 + lane;       // 512 slots of 16B
      const int row = slot >> 2;
      const int cgc = ((slot & 3) ^ ((row >> 1) & 3)) << 3;
      gload16(Bt + (size_t)(bcol * 128 + row) * K + s * 32 + cgc,
              Bs + b * BSZ + (t * 256 + wave * 64) * 8);
    }
  };

  issue(0, 0);

#pragma unroll 1
  for (int k = 0; k < NS; ++k) {
    __syncthreads();   // step-k loads landed; step-(k-1) reads closed
    if (k + 1 < NS) issue((k + 1) & 1, k + 1);   // flies under this compute

    const u16* Ab = As + (k & 1) * ASZ;
    const u16* Bb = Bs + (k & 1) * BSZ;
    bf16x8 af[NI], bfm[4];
#pragma unroll
    for (int i = 0; i < NI; i++)
      af[i] = *(const bf16x8*)(Ab + (wr * (BM / 2) + i * 16 + l15) * 32 +
                               ((quad ^ ((l15 >> 1) & 3)) << 3));
#pragma unroll
    for (int j = 0; j < 4; j++)
      bfm[j] = *(const bf16x8*)(Bb + (wc * 64 + j * 16 + l15) * 32 +
                                ((quad ^ ((l15 >> 1) & 3)) << 3));
    __builtin_amdgcn_s_setprio(1);
#pragma unroll
    for (int i = 0; i < NI; i++)
#pragma unroll
      for (int j = 0; j < 4; j++)
        acc[i][j] = __builtin_amdgcn_mfma_f32_16x16x32_bf16(af[i], bfm[j], acc[i][j], 0, 0, 0);
    __builtin_amdgcn_s_setprio(0);
  }

  if (MODE == 2) {
    // stage C-tile (bf16) into LDS as Ct[n][m], XOR-swizzled 16B chunks:
    // u16 addr = n*128 + ((mchunk ^ (n&15))<<3) + (m&7). Then coalesced Vt
    // writes: 16 lanes x 16B = 256B contiguous per column.
    __syncthreads();   // all waves done with A/B buffers
    u16* Ct = LB;      // 128*128 u16 = 32 KB
#pragma unroll
    for (int i = 0; i < NI; i++)
#pragma unroll
      for (int j = 0; j < 4; j++) {
        const int n = wc * 64 + j * 16 + l15;
        const float bv = bias[bcol * 128 + n];
        const int m = wr * (BM / 2) + i * 16 + quad * 4;
        const int mc = m >> 3;
        u32x2 pd;
        pd.x = pk2(acc[i][j][0] + bv, acc[i][j][1] + bv);
        pd.y = pk2(acc[i][j][2] + bv, acc[i][j][3] + bv);
        *(u32x2*)(Ct + n * 128 + ((mc ^ (n & 15)) << 3) + (m & 7)) = pd;
      }
    __syncthreads();
    const int c0 = bcol * 128, sr0 = brow * BM;
    const int bb = sr0 >> 11, sbase = sr0 & (S_LEN - 1);
#pragma unroll
    for (int p = 0; p < 8; p++) {
      const int idx = p * 256 + tid;
      const int cl = idx >> 4, sc = idx & 15;
      *(u32x4*)((u16*)Cv + ((size_t)(bb * 1024 + c0 + cl)) * S_LEN + sbase + sc * 8) =
          *(const u32x4*)(Ct + cl * 128 + ((sc ^ (cl & 15)) << 3));
    }
    return;
  }

#pragma unroll
  for (int i = 0; i < NI; i++)
#pragma unroll
    for (int j = 0; j < 4; j++) {
      const int col = bcol * 128 + wc * 64 + j * 16 + l15;
      const float bv = bias[col];
#pragma unroll
      for (int r = 0; r < 4; r++) {
        const int row = brow * BM + wr * (BM / 2) + i * 16 + quad * 4 + r;
        if (MODE == 1)
          ((float*)Cv)[(size_t)row * DMODEL + col] = acc[i][j][r] + bv;
        else if (MODE == 3)
          ((u16*)Cv)[(size_t)row * DMODEL + col] = f2b((acc[i][j][r] + bv) * EXP2SCALE);
        else
          ((u16*)Cv)[(size_t)row * DMODEL + col] = f2b(acc[i][j][r] + bv);
      }
    }
}

__global__ __launch_bounds__(256, 4) void gemm_qkv(
    const u16* __restrict__ Qx, const u16* __restrict__ Kx, const u16* __restrict__ Vx,
    const u16* __restrict__ Wqt, const u16* __restrict__ Wkt, const u16* __restrict__ Wvt,
    const float* __restrict__ bq, const float* __restrict__ bk, const float* __restrict__ bv,
    u16* __restrict__ Qp, u16* __restrict__ Kp, u16* __restrict__ Vt) {
  __shared__ u16 LB[16384];   // 32 KB: A dbuf 8K u16 + B dbuf 8K u16; Ct reuse
  const int z = blockIdx.z;
  if (z == 2) {
    gemm_body<2, 128>(Vx, Wvt, bv, Vt, LB);
  } else if (z == 0) {
    gemm_body<3, 128>(Qx, Wqt, bq, Qp, LB);   // Q pre-scaled by exp2-scale
  } else {
    gemm_body<0, 128>(Kx, Wkt, bk, Kp, LB);
  }
}

// BM=64: 512 blocks -> 2 blocks/CU for the single-slice output GEMM
__global__ __launch_bounds__(256, 4) void gemm_out(
    const u16* __restrict__ A, const u16* __restrict__ Bt,
    const float* __restrict__ bias, float* __restrict__ C) {
  __shared__ u16 LB[12288];   // 24 KB: A dbuf 4K u16 + B dbuf 8K u16
  gemm_body<1, 64>(A, Bt, bias, C, LB);
}

// ---------------- flash attention, v8 (proven 48us): 8-wave split-K, K+V LDS
#define TILE_COMPUTE(ksb, vsb)                                                     \
  do {                                                                             \
    f32x16 sA = {}, sB = {};                                                       \
    __builtin_amdgcn_s_setprio(1);                                                 \
    _Pragma("unroll") for (int c = 0; c < 4; c++) {                                \
      bf16x8 ka0 = *(const bf16x8*)((ksb) + off[c]);                               \
      bf16x8 ka1 = *(const bf16x8*)((ksb) + off[c] + 2048);                        \
      sA = __builtin_amdgcn_mfma_f32_32x32x16_bf16(ka0, qf[c], sA, 0, 0, 0);       \
      sB = __builtin_amdgcn_mfma_f32_32x32x16_bf16(ka1, qf[c], sB, 0, 0, 0);       \
    }                                                                              \
    __builtin_amdgcn_s_setprio(0);                                                 \
    bf16x8 pf[4];                                                                  \
    _Pragma("unroll") for (int kb = 0; kb < 2; kb++) {                             \
      const f32x16 s = kb ? sB : sA;                                               \
      unsigned int cc[8];                                                          \
      _Pragma("unroll") for (int m = 0; m < 8; m++)                                \
        cc[m] = cvtpk(__builtin_amdgcn_exp2f(s[2 * m]),                            \
                      __builtin_amdgcn_exp2f(s[2 * m + 1]));                       \
      plswap(cc[0], cc[2]);                                                        \
      plswap(cc[1], cc[3]);                                                        \
      plswap(cc[4], cc[6]);                                                        \
      plswap(cc[5], cc[7]);                                                        \
      union { unsigned int u[4]; bf16x8 v; } f0, f1;                               \
      f0.u[0] = cc[0]; f0.u[1] = cc[1]; f0.u[2] = cc[2]; f0.u[3] = cc[3];          \
      f1.u[0] = cc[4]; f1.u[1] = cc[5]; f1.u[2] = cc[6]; f1.u[3] = cc[7];          \
      pf[2 * kb] = f0.v; pf[2 * kb + 1] = f1.v;                                    \
    }                                                                              \
    __builtin_amdgcn_s_setprio(1);                                                 \
    _Pragma("unroll") for (int g = 0; g < 4; g++) {                                \
      bf16x8 v0 = *(const bf16x8*)((vsb) + off[g]);                                \
      bf16x8 v1 = *(const bf16x8*)((vsb) + off[g] + 2048);                         \
      lacc  = __builtin_amdgcn_mfma_f32_32x32x16_bf16(pf[g], ones, lacc, 0, 0, 0); \
      oacc0 = __builtin_amdgcn_mfma_f32_32x32x16_bf16(pf[g], v0, oacc0, 0, 0, 0);  \
      oacc1 = __builtin_amdgcn_mfma_f32_32x32x16_bf16(pf[g], v1, oacc1, 0, 0, 0);  \
    }                                                                              \
    __builtin_amdgcn_s_setprio(0);                                                 \
  } while (0)

// each wave stages 4 KB (4 gloads) of its assigned tile region per step
#define ISSUE(buf, kt)                                                            \
  do {                                                                            \
    if (wave < 4) {                                                               \
      const u16* g = srcK + (size_t)(kt) * 64 * DMODEL;                           \
      _Pragma("unroll") for (int j = 0; j < 4; j++)                               \
        gload16(g + (size_t)j * 8 * DMODEL, dst0 + (buf) * 4096 + j * 512);       \
    } else {                                                                      \
      const u16* g = srcV + (kt) * 64;                                            \
      _Pragma("unroll") for (int j = 0; j < 4; j++)                               \
        gload16(g + (size_t)j * 8 * S_LEN, dst0 + (buf) * 4096 + j * 512);        \
    }                                                                             \
  } while (0)

__global__ __launch_bounds__(512, 4) void attn(const u16* __restrict__ Qp,
                                               const u16* __restrict__ Kp,
                                               const u16* __restrict__ Vt,
                                               u16* __restrict__ Op) {
  // 64 KB: Ks[kh][buf][64*64] at 0, Vs[kh][buf][64*64] at 16384 (u16 units)
  __shared__ u16 LB[32768];

  const int tid = threadIdx.x;
  const int wave = tid >> 6, lane = tid & 63;
  const int row31 = lane & 31, hl = lane >> 5;
  const int qg = wave & 3, kh = wave >> 2;     // compute roles

  // XCD-chunked swizzle over 512 blocks
  const int id = blockIdx.x + (blockIdx.y << 4) + (blockIdx.z << 8);
  const int sw = ((id & 7) << 6) + (id >> 3);
  const int qt = sw & 15, h = (sw >> 4) & 15, b = sw >> 8;
  const int s0 = qt * 128;

  const size_t baseK = ((size_t)(b * S_LEN)) * DMODEL + h * DHEAD;
  const size_t baseV = ((size_t)((b * NHEAD + h) * DHEAD)) * S_LEN;

  // staging roles: waves 0-3 stage K, 4-7 stage V; khd = key-half staged,
  // sub = which 32-row half of the 64-row tile. Pre-swizzled source (rule #21).
  const int sub = wave & 1, khd = (wave >> 1) & 1;
  const int rl = lane >> 3, cl = lane & 7;
  const int cg8 = (cl ^ rl) << 3;
  const u16* srcK = Kp + baseK + (size_t)(khd * 1024 + sub * 32 + rl) * DMODEL + cg8;
  const u16* srcV = Vt + baseV + (size_t)(sub * 32 + rl) * S_LEN + khd * 1024 + cg8;
  u16* dst0 = LB + (wave >= 4 ? 16384 : 0) + khd * 8192 + (sub * 32) * 64;

  // compute-side LDS bases for this wave's key-half
  const u16* kcb = LB + kh * 8192;
  const u16* vcb = LB + 16384 + kh * 8192;

  // LDS read offsets (u16), swizzled chunks
  int off[4];
#pragma unroll
  for (int c = 0; c < 4; c++)
    off[c] = row31 * 64 + ((((c << 1) + hl) ^ (row31 & 7)) << 3);

  // all-ones B fragment for the l-vector MFMA
  bf16x8 ones;
  {
    union { u16 a[8]; bf16x8 v; } c;
#pragma unroll
    for (int j = 0; j < 8; j++) c.a[j] = 0x3F80;
    ones = c.v;
  }

  // Q fragments (B-operand of S^T): col = q = row31, k = c*16 + hl*8 + j
  bf16x8 qf[4];
#pragma unroll
  for (int c = 0; c < 4; c++)
    qf[c] = *(const bf16x8*)(Qp +
        ((size_t)(b * S_LEN + s0 + qg * 32 + row31)) * DMODEL +
        h * DHEAD + c * 16 + hl * 8);

  f32x16 oacc0 = {}, oacc1 = {};
  f32x16 lacc = {};

  // prologue: tile 0 into buf0
  ISSUE(0, 0);

#pragma unroll 1
  for (int kt = 0; kt < 16; kt += 2) {
    __syncthreads();             // drains buf0 loads; prev buf1 reads done
    ISSUE(1, kt + 1);            // next tile flies under this compute
    TILE_COMPUTE(kcb, vcb);
    __syncthreads();             // drains buf1 loads; buf0 reads done
    if (kt + 2 < 16) ISSUE(0, kt + 2);
    TILE_COMPUTE(kcb + 4096, vcb + 4096);
  }

  // ---- split-K merge: kh=1 waves publish partials via LDS (48 KB of LB)
  __syncthreads();
  float* M = ((float*)LB) + qg * 3072;  // 12 KB region per q-group
  if (kh == 1) {
#pragma unroll
    for (int r = 0; r < 16; r++) {
      M[r * 64 + lane]        = oacc0[r];
      M[1024 + r * 64 + lane] = oacc1[r];
      M[2048 + r * 64 + lane] = lacc[r];
    }
  }
  __syncthreads();
  if (kh == 0) {
#pragma unroll
    for (int r = 0; r < 16; r++) {
      const float o0 = oacc0[r] + M[r * 64 + lane];
      const float o1 = oacc1[r] + M[1024 + r * 64 + lane];
      const float ls = lacc[r] + M[2048 + r * 64 + lane];
      const float inv = 1.0f / ls;
      const int qrow = (r & 3) + 8 * (r >> 2) + 4 * hl;
      const size_t rb = ((size_t)(b * S_LEN + s0 + qg * 32 + qrow)) * DMODEL + h * DHEAD;
      Op[rb + row31]      = f2b(o0 * inv);
      Op[rb + 32 + row31] = f2b(o1 * inv);
    }
  }
}

extern "C" void kernel_launch(void* const* d_in, const int* in_sizes, int n_in,
                              void* d_out, int out_size, void* d_ws, size_t ws_size,
                              hipStream_t stream) {
  const float* q  = (const float*)d_in[0];
  const float* k  = (const float*)d_in[1];
  const float* v  = (const float*)d_in[2];
  const float* Wq = (const float*)d_in[3];
  const float* bq = (const float*)d_in[4];
  const float* Wk = (const float*)d_in[5];
  const float* bk = (const float*)d_in[6];
  const float* Wv = (const float*)d_in[7];
  const float* bv = (const float*)d_in[8];
  const float* Wo = (const float*)d_in[9];
  const float* bo = (const float*)d_in[10];

  char* w = (char*)d_ws;
  const size_t WSZ = (size_t)DMODEL * DMODEL * 2;  // 2 MB per transposed weight
  const size_t XSZ = (size_t)MROWS * DMODEL * 2;   // 8 MB per bf16 activation
  u16* Wqt = (u16*)(w);
  u16* Wkt = (u16*)(w + WSZ);
  u16* Wvt = (u16*)(w + 2 * WSZ);
  u16* Wot = (u16*)(w + 3 * WSZ);
  u16* Qx  = (u16*)(w + 4 * WSZ);
  u16* Kx  = (u16*)(w + 4 * WSZ + XSZ);
  u16* Vx  = (u16*)(w + 4 * WSZ + 2 * XSZ);
  u16* Qp  = (u16*)(w + 4 * WSZ + 3 * XSZ);
  u16* Kp  = (u16*)(w + 4 * WSZ + 4 * XSZ);
  u16* Vt  = (u16*)(w + 4 * WSZ + 5 * XSZ);
  u16* Op  = (u16*)(w + 4 * WSZ + 6 * XSZ);  // total 64 MB

  prep<<<dim3(2048, 1, 7), 256, 0, stream>>>(q, k, v, Wq, Wk, Wv, Wo,
                                             Qx, Kx, Vx, Wqt, Wkt, Wvt, Wot);
  gemm_qkv<<<dim3(8, 32, 3), 256, 0, stream>>>(Qx, Kx, Vx, Wqt, Wkt, Wvt,
                                               bq, bk, bv, Qp, Kp, Vt);
  attn<<<dim3(16, 16, 2), 512, 0, stream>>>(Qp, Kp, Vt, Op);
  gemm_out<<<dim3(8, 64, 1), 256, 0, stream>>>(Op, Wot, bo, (float*)d_out);
}